// Round 8
// baseline (586.160 us; speedup 1.0000x reference)
//
#include <hip/hip_runtime.h>
#include <hip/hip_bf16.h>

typedef __bf16 bf16;
typedef unsigned long long u64;
typedef __bf16 bf16x8 __attribute__((ext_vector_type(8)));
typedef __bf16 bf16x4 __attribute__((ext_vector_type(4)));
typedef float f32x4 __attribute__((ext_vector_type(4)));

#define NB 4
#define T 8192
#define C 128
#define NBLK 40
#define XS 136   // LDS row stride (bf16): 128 ch + 8 pad

#define MFMA(a, b, c) __builtin_amdgcn_mfma_f32_16x16x32_bf16(a, b, c, 0, 0, 0)

__device__ __forceinline__ float bf2f(bf16 x){ return (float)x; }
__device__ __forceinline__ bf16 f2bf(float x){ return (bf16)x; }

__device__ __forceinline__ float ld(const void* p, int i, int isbf){
    return isbf ? bf2f(((const bf16*)p)[i]) : ((const float*)p)[i];
}

// Coherent 8B load (relaxed agent atomic -> bypasses stale L1/L2).
__device__ __forceinline__ bf16x4 ld8(const bf16* p){
    u64 v = __hip_atomic_load((const u64*)p, __ATOMIC_RELAXED, __HIP_MEMORY_SCOPE_AGENT);
    return __builtin_bit_cast(bf16x4, v);
}
// Coherent 16B store via asm (inputs only -> safe), caller drains vmcnt.
__device__ __forceinline__ void st16c(bf16* p, f32x4 v){
    asm volatile("global_store_dwordx4 %0, %1, off sc0 sc1" :: "v"(p), "v"(v) : "memory");
}

// Detect input dtype from x's raw bits (bf16 -> low u16s have sane exponents).
__global__ __launch_bounds__(64) void k_detect(const unsigned short* __restrict__ u,
                                               int* __restrict__ flag){
    unsigned short v = u[threadIdx.x * 2];
    int e = (v >> 7) & 255;
    bool sane = (e >= 100 && e <= 140) || ((v & 0x7FFF) == 0);
    unsigned long long m = __ballot(sane);
    if (threadIdx.x == 0) *flag = (__popcll(m) >= 48) ? 1 : 0;
}

// Canonicalize inputs (8 elems per thread).
// weff [40][256][256] bf16: weff[blk][o][c]=cw[blk][o][c][0] (t-d), [o][128+c]=cw[..][1] (t)
__global__ __launch_bounds__(256) void k_prep(
    const void* __restrict__ conv_w, const void* __restrict__ post_w,
    const void* __restrict__ lin1_w, const void* __restrict__ lin2_w,
    const void* __restrict__ x,      const void* __restrict__ conv_b,
    const void* __restrict__ post_b, const void* __restrict__ pre_w,
    const void* __restrict__ pre_b,  const void* __restrict__ lin1_b,
    const void* __restrict__ lin2_b,
    bf16* __restrict__ weff, bf16* __restrict__ pwc,
    bf16* __restrict__ w1c,  bf16* __restrict__ w2c,
    float* __restrict__ xc,  float* __restrict__ cbf,
    float* __restrict__ pbf, float* __restrict__ misc,
    const int* __restrict__ flag){
    int f = *flag;
    int g = blockIdx.x * 256 + threadIdx.x;
    if (g < 327680){                 // weff: 40*256*256/8 granules
        int blk = g >> 13, r = g & 8191, o = r >> 5, j = r & 31;
        int k = (j >= 16) ? 1 : 0;
        int base = blk * 65536 + o * 256 + (j * 8 - k * 128) * 2 + k;
        bf16x8 v;
#pragma unroll
        for (int m = 0; m < 8; m++) v[m] = f2bf(ld(conv_w, base + m * 2, f));
        *(bf16x8*)(weff + (size_t)g * 8) = v;
    } else if (g < 409600){          // pwc
        int e = (g - 327680) * 8;
        bf16x8 v;
#pragma unroll
        for (int m = 0; m < 8; m++) v[m] = f2bf(ld(post_w, e + m, f));
        *(bf16x8*)(pwc + e) = v;
    } else if (g < 411648){          // w1c
        int e = (g - 409600) * 8;
        bf16x8 v;
#pragma unroll
        for (int m = 0; m < 8; m++) v[m] = f2bf(ld(lin1_w, e + m, f));
        *(bf16x8*)(w1c + e) = v;
    } else if (g < 413696){          // w2c
        int e = (g - 411648) * 8;
        bf16x8 v;
#pragma unroll
        for (int m = 0; m < 8; m++) v[m] = f2bf(ld(lin2_w, e + m, f));
        *(bf16x8*)(w2c + e) = v;
    } else if (g < 417792){          // xc (f32)
        int e = (g - 413696) * 8;
#pragma unroll
        for (int m = 0; m < 8; m++) xc[e + m] = ld(x, e + m, f);
    } else if (g < 419072){          // cbf
        int e = (g - 417792) * 8;
#pragma unroll
        for (int m = 0; m < 8; m++) cbf[e + m] = ld(conv_b, e + m, f);
    } else if (g < 419712){          // pbf
        int e = (g - 419072) * 8;
#pragma unroll
        for (int m = 0; m < 8; m++) pbf[e + m] = ld(post_b, e + m, f);
    } else if (g < 419808){          // misc
        int e = (g - 419712) * 8;
#pragma unroll
        for (int m = 0; m < 8; m++){
            int idx = e + m;
            if      (idx < 384) misc[idx] = ld(pre_w,  idx,       f);
            else if (idx < 512) misc[idx] = ld(pre_b,  idx - 384, f);
            else if (idx < 640) misc[idx] = ld(lin1_b, idx - 512, f);
            else                misc[idx] = ld(lin2_b, idx - 640, f);
        }
    }
}

__device__ __forceinline__ void wait_ge(unsigned* p, unsigned v){
    int guard = 0;
    while (__hip_atomic_load(p, __ATOMIC_RELAXED, __HIP_MEMORY_SCOPE_AGENT) < v){
        __builtin_amdgcn_s_sleep(1);
        if (++guard > (1 << 22)) break;   // failsafe against protocol bugs
    }
    asm volatile("" ::: "memory");
}

// Store own cols [128-nst, 128) (= 192-tile rows 64+[128-nst,128)) to dst, drain.
__device__ __forceinline__ void tail_store192(const bf16* Xo, bf16* dst, int nst, int tid){
    int ngr = nst * 16;
    for (int g = tid; g < ngr; g += 512){
        int rr = 128 - nst + (g >> 4), co = (g & 15) * 8;
        f32x4 v = *(const f32x4*)(Xo + (64 + rr) * XS + co);
        st16c(dst + (size_t)rr * C + co, v);
    }
    asm volatile("s_waitcnt vmcnt(0)" ::: "memory");
}

// Persistent kernel, 256 WGs x 512 threads, 1 WG/CU (proven geometry).
//
// HALO-GROUP protocol (round-7 + causal-pad fix):
//  - layers d=1..32 run as ONE group on a 192-col tile (64-col halo, Σd=63).
//    One handshake at entry; then 6 layers of local compute, 3 barriers each.
//  - FIX(r8): SLAB 0 must preserve causal zero-padding — the reference
//    zero-pads EVERY layer's input (h[t<0]=0). The group was computing
//    nonzero h in slab 0's halo (bias->GLU->post junk) and feeding it to
//    cols [0,d) of the next layer. Deterministic ~0.08 error (r6 & r7
//    failed identically). Fix: slab 0 writes ZERO to halo h_next rows each
//    layer; clamped taps then read true zeros -> exact reference semantics.
//  - layers d=64..512 keep the round-5 merged 5-barrier structure.
// prog[w] = last stored k; cons[w] = last consumed k (k = 1..20).
__global__ __launch_bounds__(512, 2) void k_main(
    const float* __restrict__ xc,  const float* __restrict__ misc,
    const bf16* __restrict__ weff, const float* __restrict__ cbf,
    const bf16* __restrict__ pwc,  const float* __restrict__ pbf,
    const bf16* __restrict__ w1c,  const bf16* __restrict__ w2c,
    bf16* __restrict__ hA, bf16* __restrict__ hB,
    unsigned* __restrict__ prog, unsigned* __restrict__ cons,
    void* __restrict__ outv, const int* __restrict__ flag)
{
    __shared__ __align__(16) bf16 XoA[192 * XS];  // 52,224 B
    __shared__ __align__(16) bf16 XoB[192 * XS];  // 52,224 B
    bf16* Xh = XoB;                               // alias: staging/S for d>=64 layers

    int tid  = threadIdx.x;
    int wg   = blockIdx.x;             // 256
    int b    = wg >> 6;
    int slab = wg & 63;
    int t0   = slab * 128;
    int wv = tid >> 6, ln = tid & 63, lo = ln & 15, quad = ln >> 4;
    const size_t hb = (size_t)b * T * C;

    float hreg[32];   // own cols: h[ch wv*16+quad*4+r][col t0+ct*16+lo]
    float ssum[32];

    // ---- pre-net: hreg + XoA rows 64..191; store 64-col tail (k=1) ----
    {
        const float* xr = xc + b * T;
#pragma unroll
        for (int ct = 0; ct < 8; ct++){
            int t = t0 + ct * 16 + lo;
            float x0 = (t >= 2) ? xr[t - 2] : 0.f;
            float x1 = (t >= 1) ? xr[t - 1] : 0.f;
            float x2 = xr[t];
            bf16x4 hv;
#pragma unroll
            for (int r = 0; r < 4; r++){
                int c = wv * 16 + quad * 4 + r;
                float acc = misc[384 + c] + misc[c*3]*x0 + misc[c*3+1]*x1 + misc[c*3+2]*x2;
                hreg[ct * 4 + r] = acc;
                hv[r] = f2bf(acc);
            }
            *(bf16x4*)(XoA + (64 + ct * 16 + lo) * XS + wv * 16 + quad * 4) = hv;
        }
    }
#pragma unroll
    for (int i = 0; i < 32; i++) ssum[i] = 0.f;
    __syncthreads();
    if (slab < 63) tail_store192(XoA, hB + hb + (size_t)t0 * C, 64, tid);  // k=1 -> hB
    __syncthreads();
    if (tid == 0)
        __hip_atomic_store(prog + wg, 1u, __ATOMIC_RELAXED, __HIP_MEMORY_SCOPE_AGENT);

    // ---- 4 dilation cycles ----
    for (int c = 0; c < 4; c++){
        const int ib = 10 * c;

        // ======== GROUP: layers ib..ib+5 (d = 1..32) ========
        {
            float hregH[16];    // f32 halo h: cols t0-64+ct*16+lo, ct<4
            const int k_entry = 5 * c + 1;
            const bf16* hEnt = (k_entry & 1) ? hB : hA;
            if (slab >= 1) wait_ge(prog + (wg - 1), (unsigned)k_entry);
            {   // stage halo h^{ib} cols [t0-64, t0) -> XoA rows 0..63
                int tbase = t0 - 64;
#pragma unroll
                for (int jj = 0; jj < 4; jj++){
                    int g = jj * 512 + tid;       // 2048 granules of 8B
                    int row = g >> 5, c4 = (g & 31) << 2;
                    int t = tbase + row;
                    bf16x4 v = {};
                    if (t >= 0) v = ld8(hEnt + hb + (size_t)t * C + c4);
                    *(bf16x4*)(XoA + row * XS + c4) = v;
                }
            }
            __syncthreads();                                 // entry: halo visible
            if (tid == 0)
                __hip_atomic_store(cons + wg, (unsigned)k_entry,
                                   __ATOMIC_RELAXED, __HIP_MEMORY_SCOPE_AGENT);
#pragma unroll
            for (int ct = 0; ct < 4; ct++){                  // f32 halo regs
                bf16x4 hv = *(const bf16x4*)(XoA + (ct*16 + lo) * XS + wv*16 + quad*4);
#pragma unroll
                for (int r = 0; r < 4; r++) hregH[ct * 4 + r] = bf2f(hv[r]);
            }

            for (int l = 0; l < 6; l++){
                const int d = 1 << l;
                bf16* Xc = (l & 1) ? XoB : XoA;
                bf16* Xn = (l & 1) ? XoA : XoB;
                const bf16* wb  = weff + ((size_t)(ib + l) << 16);
                const bf16* pwb = pwc + (ib + l) * 16384;
                const float* cb = cbf + (ib + l) * 256;
                const float* pb = pbf + (ib + l) * 128;

                f32x4 cacc0[12] = {}, cacc1[12] = {};
#pragma unroll
                for (int kk = 0; kk < 4; kk++){
                    int ko = kk * 32 + quad * 8;
                    bf16x8 a0d = *(const bf16x8*)(wb + (size_t)(wv*16 + lo) * 256 + ko);
                    bf16x8 a1d = *(const bf16x8*)(wb + (size_t)(128 + wv*16 + lo) * 256 + ko);
                    bf16x8 a0t = *(const bf16x8*)(wb + (size_t)(wv*16 + lo) * 256 + 128 + ko);
                    bf16x8 a1t = *(const bf16x8*)(wb + (size_t)(128 + wv*16 + lo) * 256 + 128 + ko);
#pragma unroll
                    for (int ct = 0; ct < 12; ct++){
                        int rt = ct * 16 + lo;
                        int rd = rt - d; rd = (rd < 0) ? 0 : rd;   // invalid cols: clamp
                        bf16x8 bt = *(const bf16x8*)(Xc + rt * XS + ko);
                        bf16x8 bd = *(const bf16x8*)(Xc + rd * XS + ko);
                        cacc0[ct] = MFMA(a0d, bd, cacc0[ct]);
                        cacc0[ct] = MFMA(a0t, bt, cacc0[ct]);
                        cacc1[ct] = MFMA(a1d, bd, cacc1[ct]);
                        cacc1[ct] = MFMA(a1t, bt, cacc1[ct]);
                    }
                }
                // GLU -> S into Xn (ssum only for own cols ct>=4)
#pragma unroll
                for (int ct = 0; ct < 12; ct++){
                    bf16x4 sv;
#pragma unroll
                    for (int r = 0; r < 4; r++){
                        int j = wv * 16 + quad * 4 + r;
                        float a = cacc0[ct][r] + cb[j];
                        float g = cacc1[ct][r] + cb[128 + j];
                        float s = a * __builtin_amdgcn_rcpf(1.f + __expf(-g));
                        if (ct >= 4) ssum[(ct - 4) * 4 + r] += s;
                        sv[r] = f2bf(s);
                    }
                    *(bf16x4*)(Xn + (ct * 16 + lo) * XS + wv * 16 + quad * 4) = sv;
                }
                __syncthreads();                             // G1: S visible
                f32x4 pacc[12] = {};
#pragma unroll
                for (int kk = 0; kk < 4; kk++){
                    bf16x8 pa = *(const bf16x8*)(pwb + (wv*16 + lo) * 128 + kk*32 + quad*8);
#pragma unroll
                    for (int ct = 0; ct < 12; ct++){
                        bf16x8 pbv = *(const bf16x8*)(Xn + (ct*16 + lo) * XS + kk*32 + quad*8);
                        pacc[ct] = MFMA(pa, pbv, pacc[ct]);
                    }
                }
                __syncthreads();                             // G2: S reads done
                // h_next -> Xn (halo from f32 hregH; own from f32 hreg)
                // FIX r8: slab 0's halo cols are t<0 -> causal zero-padding
                // requires h==0 there at EVERY layer input. Write zeros.
#pragma unroll
                for (int ct = 0; ct < 12; ct++){
                    bf16x4 hv;
                    if (ct < 4){
#pragma unroll
                        for (int r = 0; r < 4; r++){
                            hregH[ct * 4 + r] += pacc[ct][r] + pb[wv*16 + quad*4 + r];
                            hv[r] = f2bf(hregH[ct * 4 + r]);
                        }
                        if (slab == 0){ bf16x4 z = {}; hv = z; }
                    } else {
#pragma unroll
                        for (int r = 0; r < 4; r++){
                            hreg[(ct - 4) * 4 + r] += pacc[ct][r] + pb[wv*16 + quad*4 + r];
                            hv[r] = f2bf(hreg[(ct - 4) * 4 + r]);
                        }
                    }
                    *(bf16x4*)(Xn + (ct * 16 + lo) * XS + wv * 16 + quad * 4) = hv;
                }
                __syncthreads();                             // G3: h_next visible
            }
            // group end: h^{ib+6} in XoA; store 64-col tail (k = 5c+2)
            {
                const int k_st = 5 * c + 2;
                bool stg = (slab + 1 <= 63);
                if (stg){
                    if (c >= 1 && slab + 4 <= 63)            // overwrites h-k=5c (Dr=4)
                        wait_ge(cons + (wg + 4), (unsigned)(5 * c));
                    tail_store192(XoA, ((k_st & 1) ? hB : hA) + hb + (size_t)t0 * C, 64, tid);
                }
                __syncthreads();
                if (tid == 0)
                    __hip_atomic_store(prog + wg, (unsigned)k_st,
                                       __ATOMIC_RELAXED, __HIP_MEMORY_SCOPE_AGENT);
            }
        }

        // ======== per-layer: j = 6..9 (d = 64..512), round-5 structure ========
        for (int j = 6; j <= 9; j++){
            const int i = ib + j;
            const int d = 64 << (j - 6);
            const int D = (j <= 7) ? 1 : ((j == 8) ? 2 : 4);
            const int k_cons = 5 * c + (j - 4);
            const int k_st   = k_cons + 1;
            const int nst    = (j == 9) ? 64 : 128;
            const bool last  = (i == NBLK - 1);
            const int Dr_st  = (j == 6) ? 1 : ((j == 7) ? 2 : ((j == 8) ? 4 : 1));
            const bool do_store = !last && (slab + Dr_st <= 63);
            const int kow    = k_st - 2;
            const int Dr_ow  = (j == 9) ? 2 : 1;
            const bf16* hin  = (k_cons & 1) ? hB : hA;
            bf16*       hout = (k_st & 1) ? hB : hA;
            const bf16* wb   = weff + ((size_t)i << 16);
            const bf16* pwb  = pwc  + i * 16384;
            const float* cb  = cbf + i * 256;
            const float* pb  = pbf + i * 128;

            f32x4 cacc0[8] = {}, cacc1[8] = {};
            // A: tap-t MFMA from XoA rows 64..191 (no deps)
#pragma unroll
            for (int kk = 0; kk < 4; kk++){
                int ko = 128 + kk * 32 + quad * 8;
                bf16x8 a0 = *(const bf16x8*)(wb + (size_t)(wv*16 + lo) * 256 + ko);
                bf16x8 a1 = *(const bf16x8*)(wb + (size_t)(128 + wv*16 + lo) * 256 + ko);
#pragma unroll
                for (int ct = 0; ct < 8; ct++){
                    bf16x8 bf_ = *(const bf16x8*)(XoA + (64 + ct*16 + lo) * XS + kk*32 + quad*8);
                    cacc0[ct] = MFMA(a0, bf_, cacc0[ct]);
                    cacc1[ct] = MFMA(a1, bf_, cacc1[ct]);
                }
            }
            if (slab >= D) wait_ge(prog + (wg - D), (unsigned)k_cons);
            // B: stage Xh rows 0..127 = cols [t0-d, t0+128-d)
            {
                int tbase = t0 - d;
#pragma unroll
                for (int jj = 0; jj < 8; jj++){
                    int g = jj * 512 + tid;
                    int row = g >> 5, c4 = (g & 31) << 2;
                    int t = tbase + row;
                    bf16x4 v = {};
                    if (t >= t0)      v = *(const bf16x4*)(XoA + (64 + t - t0) * XS + c4);
                    else if (t >= 0)  v = ld8(hin + hb + (size_t)t * C + c4);
                    *(bf16x4*)(Xh + row * XS + c4) = v;
                }
            }
            __syncthreads();                                 // S1
            if (!last && tid == 0)
                __hip_atomic_store(cons + wg, (unsigned)k_cons,
                                   __ATOMIC_RELAXED, __HIP_MEMORY_SCOPE_AGENT);
            // C: tap t-d MFMA from Xh
#pragma unroll
            for (int kk = 0; kk < 4; kk++){
                int ko = kk * 32 + quad * 8;
                bf16x8 a0 = *(const bf16x8*)(wb + (size_t)(wv*16 + lo) * 256 + ko);
                bf16x8 a1 = *(const bf16x8*)(wb + (size_t)(128 + wv*16 + lo) * 256 + ko);
#pragma unroll
                for (int ct = 0; ct < 8; ct++){
                    bf16x8 bf_ = *(const bf16x8*)(Xh + (ct*16 + lo) * XS + kk*32 + quad*8);
                    cacc0[ct] = MFMA(a0, bf_, cacc0[ct]);
                    cacc1[ct] = MFMA(a1, bf_, cacc1[ct]);
                }
            }
            __syncthreads();                                 // S2
            // D: GLU -> ssum; S -> Xh (unless last)
#pragma unroll
            for (int ct = 0; ct < 8; ct++){
                bf16x4 sv;
#pragma unroll
                for (int r = 0; r < 4; r++){
                    int jj = wv * 16 + quad * 4 + r;
                    float a = cacc0[ct][r] + cb[jj];
                    float g = cacc1[ct][r] + cb[128 + jj];
                    float s = a * __builtin_amdgcn_rcpf(1.f + __expf(-g));
                    ssum[ct * 4 + r] += s;
                    sv[r] = f2bf(s);
                }
                if (!last) *(bf16x4*)(Xh + (ct*16 + lo) * XS + wv*16 + quad*4) = sv;
            }
            if (last) break;                                 // i == 39: ssum done
            __syncthreads();                                 // S3
            // E: post MFMA + residual -> XoA rows 64..191
            {
                f32x4 pacc[8] = {};
#pragma unroll
                for (int kk = 0; kk < 4; kk++){
                    bf16x8 pa = *(const bf16x8*)(pwb + (wv*16 + lo) * 128 + kk*32 + quad*8);
#pragma unroll
                    for (int ct = 0; ct < 8; ct++){
                        bf16x8 pbv = *(const bf16x8*)(Xh + (ct*16 + lo) * XS + kk*32 + quad*8);
                        pacc[ct] = MFMA(pa, pbv, pacc[ct]);
                    }
                }
#pragma unroll
                for (int ct = 0; ct < 8; ct++){
                    bf16x4 hv;
#pragma unroll
                    for (int r = 0; r < 4; r++){
                        hreg[ct * 4 + r] += pacc[ct][r] + pb[wv*16 + quad*4 + r];
                        hv[r] = f2bf(hreg[ct * 4 + r]);
                    }
                    *(bf16x4*)(XoA + (64 + ct*16 + lo) * XS + wv*16 + quad*4) = hv;
                }
            }
            if (do_store && slab + Dr_ow <= 63)              // anti-overwrite of h^{kow}
                wait_ge(cons + (wg + Dr_ow), (unsigned)kow);
            if (j == 6 && c >= 1 && do_store && slab + 2 <= 63)  // deep remnant (r7)
                wait_ge(cons + (wg + 2), (unsigned)(5 * c - 1)); // k=5c-1 reader @ s+2
            __syncthreads();                                 // S4
            if (do_store) tail_store192(XoA, hout + hb + (size_t)t0 * C, nst, tid);
            __syncthreads();                                 // S5
            if (tid == 0)
                __hip_atomic_store(prog + wg, (unsigned)k_st,
                                   __ATOMIC_RELAXED, __HIP_MEMORY_SCOPE_AGENT);
        }
    }

    // ---- final: relu(ssum) -> lin1 -> relu -> lin2 -> out [T][B][C] ----
    const float* b1 = misc + 512;
    const float* b2 = misc + 640;
    int isbf = *flag;
    __syncthreads();          // seal last layer's Xh tap reads before overwrite
#pragma unroll
    for (int ct = 0; ct < 8; ct++){
        bf16x4 zv;
#pragma unroll
        for (int r = 0; r < 4; r++){
            float z = ssum[ct * 4 + r];
            zv[r] = f2bf(z > 0.f ? z : 0.f);
        }
        *(bf16x4*)(Xh + (ct*16 + lo) * XS + wv*16 + quad*4) = zv;
    }
    __syncthreads();
    f32x4 a1[8] = {};
#pragma unroll
    for (int kk = 0; kk < 4; kk++){
        bf16x8 pa = *(const bf16x8*)(w1c + (wv*16 + lo) * 128 + kk*32 + quad*8);
#pragma unroll
        for (int ct = 0; ct < 8; ct++){
            bf16x8 pbv = *(const bf16x8*)(Xh + (ct*16 + lo) * XS + kk*32 + quad*8);
            a1[ct] = MFMA(pa, pbv, a1[ct]);
        }
    }
    __syncthreads();
#pragma unroll
    for (int ct = 0; ct < 8; ct++){
        bf16x4 uv;
#pragma unroll
        for (int r = 0; r < 4; r++){
            int row = wv * 16 + quad * 4 + r;
            float u = a1[ct][r] + b1[row];
            uv[r] = f2bf(u > 0.f ? u : 0.f);
        }
        *(bf16x4*)(Xh + (ct*16 + lo) * XS + wv*16 + quad*4) = uv;
    }
    __syncthreads();
    f32x4 a2[8] = {};
#pragma unroll
    for (int kk = 0; kk < 4; kk++){
        bf16x8 pa = *(const bf16x8*)(w2c + (wv*16 + lo) * 128 + kk*32 + quad*8);
#pragma unroll
        for (int ct = 0; ct < 8; ct++){
            bf16x8 pbv = *(const bf16x8*)(Xh + (ct*16 + lo) * XS + kk*32 + quad*8);
            a2[ct] = MFMA(pa, pbv, a2[ct]);
        }
    }
#pragma unroll
    for (int ct = 0; ct < 8; ct++){
        int col = t0 + ct * 16 + lo;
#pragma unroll
        for (int r = 0; r < 4; r++){
            int row = wv * 16 + quad * 4 + r;
            float v = a2[ct][r] + b2[row];
            size_t oi = ((size_t)col * NB + b) * C + row;
            if (isbf) ((bf16*)outv)[oi] = f2bf(v);
            else      ((float*)outv)[oi] = v;
        }
    }
}

extern "C" void kernel_launch(void* const* d_in, const int* in_sizes, int n_in,
                              void* d_out, int out_size, void* d_ws, size_t ws_size,
                              hipStream_t stream){
    const void* x      = d_in[0];
    const void* pre_w  = d_in[1];
    const void* pre_b  = d_in[2];
    const void* conv_w = d_in[3];
    const void* conv_b = d_in[4];
    const void* post_w = d_in[5];
    const void* post_b = d_in[6];
    const void* lin1w  = d_in[7];
    const void* lin1b  = d_in[8];
    const void* lin2w  = d_in[9];
    const void* lin2b  = d_in[10];

    char* ws = (char*)d_ws;
    bf16*     hA   = (bf16*)    (ws);                   //  8,388,608 B
    bf16*     hB   = (bf16*)    (ws +  8388608);        //  8,388,608 B
    bf16*     weff = (bf16*)    (ws + 16777216);        //  5,242,880 B
    bf16*     pwc  = (bf16*)    (ws + 22020096);        //  1,310,720 B
    bf16*     w1c  = (bf16*)    (ws + 23330816);        //     32,768 B
    bf16*     w2c  = (bf16*)    (ws + 23363584);        //     32,768 B
    float*    xc   = (float*)   (ws + 23396352);        //    131,072 B
    float*    cbf  = (float*)   (ws + 23527424);        //     40,960 B
    float*    pbf  = (float*)   (ws + 23568384);        //     20,480 B
    float*    misc = (float*)   (ws + 23588864);        //      3,072 B
    int*      flag = (int*)     (ws + 23591936);        //          4 B
    unsigned* prog = (unsigned*)(ws + 23592960);        //      1,024 B
    unsigned* cons = (unsigned*)(ws + 23593984);        //      1,024 B

    hipMemsetAsync(prog, 0, 2048, stream);
    k_detect<<<1, 64, 0, stream>>>((const unsigned short*)x, flag);
    k_prep<<<1640, 256, 0, stream>>>(conv_w, post_w, lin1w, lin2w, x, conv_b,
                                     post_b, pre_w, pre_b, lin1b, lin2b,
                                     weff, pwc, w1c, w2c, xc, cbf, pbf, misc, flag);

    const float* xc_c   = xc;   const float* misc_c = misc;
    const bf16*  weff_c = weff; const float* cbf_c  = cbf;
    const bf16*  pwc_c  = pwc;  const float* pbf_c  = pbf;
    const bf16*  w1c_c  = w1c;  const bf16*  w2c_c  = w2c;
    void* out_v = d_out;        const int* flag_c = flag;
    void* ka[14] = { &xc_c, &misc_c, &weff_c, &cbf_c, &pwc_c, &pbf_c,
                     &w1c_c, &w2c_c, &hA, &hB, &prog, &cons, &out_v, &flag_c };
    hipLaunchCooperativeKernel((void*)k_main, dim3(256), dim3(512), ka, 0, stream);
}